// Round 4
// baseline (391.726 us; speedup 1.0000x reference)
//
#include <hip/hip_runtime.h>
#include <hip/hip_bf16.h>
#include <math.h>

// Problem constants
#define B_ 8
#define S_ 4096
#define E_ 1024
#define H_ 128
#define MIN_K 32
// d_out layout: filtered [B,S,E] | selection_mask [B,S] | expected_k [B]
#define OUT_MASK_OFF (B_*S_*E_)
#define OUT_EK_OFF   (B_*S_*E_ + B_*S_)

// workspace byte offsets (total 917,536 B)
#define LOGITS_OFF 0
#define SOFT_OFF   131072
#define CNT_OFF    262144
#define KROW_OFF   393216
#define W1T_HI_OFF 393248   // 16B aligned
#define W1T_LO_OFF 655392   // 16B aligned

typedef __attribute__((ext_vector_type(8))) short   frag8;   // 8 bf16 (4 VGPR)
typedef __attribute__((ext_vector_type(4))) float   fragc;   // 4 f32 acc

static __device__ __forceinline__ unsigned short bf16_rne(float f) {
  unsigned u = __float_as_uint(f);
  unsigned r = u + 0x7FFF + ((u >> 16) & 1);
  return (unsigned short)(r >> 16);
}
static __device__ __forceinline__ float bf16_to_f32(unsigned short h) {
  return __uint_as_float(((unsigned)h) << 16);
}

// ---------------------------------------------------------------------------
// Prep: w1 [E][H] f32  ->  w1t_hi/w1t_lo [H][E] bf16 (transposed, k-contiguous)
// ---------------------------------------------------------------------------
__global__ __launch_bounds__(256) void prep_w_kernel(
    const float* __restrict__ w1,
    unsigned short* __restrict__ w1t_hi, unsigned short* __restrict__ w1t_lo)
{
  int id = blockIdx.x * 256 + threadIdx.x;       // 0..32767
  int k  = id >> 5;                               // 0..1023
  int n4 = id & 31;                               // 0..31
  float4 w = *(const float4*)(w1 + k * H_ + n4 * 4);
#pragma unroll
  for (int e = 0; e < 4; ++e) {
    float f = (e == 0) ? w.x : (e == 1) ? w.y : (e == 2) ? w.z : w.w;
    unsigned short hi = bf16_rne(f);
    unsigned short lo = bf16_rne(f - bf16_to_f32(hi));
    int n = n4 * 4 + e;
    w1t_hi[n * E_ + k] = hi;
    w1t_lo[n * E_ + k] = lo;
  }
}

// ---------------------------------------------------------------------------
// Scorer v4: TLP-first. Post-mortems: v1/v2 = barrier-drain pathology
// (~5900 cyc/K-step serial); v3 = register double-buffer defeated by the
// compiler (VGPR 80 < the 128 the pipeline needed -> loads sunk to uses,
// fully serial at 2 waves/SIMD). Lesson (guide Common-mistake #5): hide
// latency with WAVES, not source-level ILP.
//   wave = 32m x 32n (mt=2, nt=2); block = 4 waves (nh 0..3 -> all 128 n);
//   grid = 1024 = 4 blocks/CU, 16 waves/CU, ALL co-resident (zero rounds).
//   K-loop: no LDS, no barriers, no unroll, no explicit prefetch — per step
//   issue 2 A-loads (x, L3-hot) + 4 B-loads (w1t, L2-hot), one waitcnt,
//   convert, 12 MFMA. 4 waves/SIMD interleave to cover the load latency.
//   __launch_bounds__(256,4) caps VGPR at 128 (est ~90: no spill possible).
// Logits bitwise identical to v1: same full-K serial acc chains, same
// hh/hl/lh order, same epilogue reduction tree.
// ---------------------------------------------------------------------------
#define KT 32
#define NTILES (E_ / KT)

__global__ __launch_bounds__(256, 4) void scorer_kernel(
    const float* __restrict__ x,
    const unsigned short* __restrict__ w1t_hi,
    const unsigned short* __restrict__ w1t_lo,
    const float* __restrict__ b1, const float* __restrict__ w2,
    const float* __restrict__ b2, float* __restrict__ logits)
{
  __shared__ float part[4][32];   // [nh group][row within 32-m tile]

  const int tid  = threadIdx.x;
  const int nh   = tid >> 6;         // wave id = n-group: cols [nh*32, nh*32+32)
  const int lane = tid & 63;
  const int l15  = lane & 15;
  const int quad = lane >> 4;
  const int m0   = blockIdx.x * 32;

  // per-lane A row pointers (rows m0 + mt*16 + l15, col base quad*8)
  const float* __restrict__ ar0 = x + (size_t)(m0 + 0  + l15) * E_ + quad * 8;
  const float* __restrict__ ar1 = x + (size_t)(m0 + 16 + l15) * E_ + quad * 8;

  // per-lane B row pointers (rows n = nh*32 + nt*16 + l15, col base quad*8)
  const size_t bo0 = (size_t)(nh * 32 + 0  + l15) * E_ + quad * 8;
  const size_t bo1 = (size_t)(nh * 32 + 16 + l15) * E_ + quad * 8;
  const unsigned short* __restrict__ bh0p = w1t_hi + bo0;
  const unsigned short* __restrict__ bh1p = w1t_hi + bo1;
  const unsigned short* __restrict__ bl0p = w1t_lo + bo0;
  const unsigned short* __restrict__ bl1p = w1t_lo + bo1;

  fragc acc00 = (fragc)(0.f), acc01 = (fragc)(0.f);
  fragc acc10 = (fragc)(0.f), acc11 = (fragc)(0.f);

#pragma unroll 1
  for (int t = 0; t < NTILES; ++t) {
    const int k = t * KT;   // element offset, same for f32 A and bf16 B rows

    // loads (compiler clusters these, single counted waitcnt before use)
    float4 a00 = *(const float4*)(ar0 + k);
    float4 a01 = *(const float4*)(ar0 + k + 4);
    float4 a10 = *(const float4*)(ar1 + k);
    float4 a11 = *(const float4*)(ar1 + k + 4);
    frag8 bh0 = *(const frag8*)(bh0p + k);
    frag8 bh1 = *(const frag8*)(bh1p + k);
    frag8 bl0 = *(const frag8*)(bl0p + k);
    frag8 bl1 = *(const frag8*)(bl1p + k);

    // convert A to split-bf16 (bitwise identical to v1's staged values)
    frag8 ah0, al0, ah1, al1;
    {
      float f0[8] = {a00.x, a00.y, a00.z, a00.w, a01.x, a01.y, a01.z, a01.w};
      float f1[8] = {a10.x, a10.y, a10.z, a10.w, a11.x, a11.y, a11.z, a11.w};
#pragma unroll
      for (int e = 0; e < 8; ++e) {
        unsigned short hi0 = bf16_rne(f0[e]);
        ah0[e] = (short)hi0;
        al0[e] = (short)bf16_rne(f0[e] - bf16_to_f32(hi0));
        unsigned short hi1 = bf16_rne(f1[e]);
        ah1[e] = (short)hi1;
        al1[e] = (short)bf16_rne(f1[e] - bf16_to_f32(hi1));
      }
    }

    // 12 MFMAs; per-acc chain order identical to v1: hh, hl, lh
    acc00 = __builtin_amdgcn_mfma_f32_16x16x32_bf16(ah0, bh0, acc00, 0, 0, 0);
    acc00 = __builtin_amdgcn_mfma_f32_16x16x32_bf16(ah0, bl0, acc00, 0, 0, 0);
    acc00 = __builtin_amdgcn_mfma_f32_16x16x32_bf16(al0, bh0, acc00, 0, 0, 0);
    acc01 = __builtin_amdgcn_mfma_f32_16x16x32_bf16(ah0, bh1, acc01, 0, 0, 0);
    acc01 = __builtin_amdgcn_mfma_f32_16x16x32_bf16(ah0, bl1, acc01, 0, 0, 0);
    acc01 = __builtin_amdgcn_mfma_f32_16x16x32_bf16(al0, bh1, acc01, 0, 0, 0);
    acc10 = __builtin_amdgcn_mfma_f32_16x16x32_bf16(ah1, bh0, acc10, 0, 0, 0);
    acc10 = __builtin_amdgcn_mfma_f32_16x16x32_bf16(ah1, bl0, acc10, 0, 0, 0);
    acc10 = __builtin_amdgcn_mfma_f32_16x16x32_bf16(al1, bh0, acc10, 0, 0, 0);
    acc11 = __builtin_amdgcn_mfma_f32_16x16x32_bf16(ah1, bh1, acc11, 0, 0, 0);
    acc11 = __builtin_amdgcn_mfma_f32_16x16x32_bf16(ah1, bl1, acc11, 0, 0, 0);
    acc11 = __builtin_amdgcn_mfma_f32_16x16x32_bf16(al1, bh1, acc11, 0, 0, 0);
  }

  // Epilogue (v1's exact tree): h = relu(acc + b1[n]); p = sum_nt h*w2[n]
  // (nt ascending fma); 16-lane butterfly; cross-wave ((g0+g1)+(g2+g3)).
  float b1v0 = b1[nh * 32 + 0  + l15], w2v0 = w2[nh * 32 + 0  + l15];
  float b1v1 = b1[nh * 32 + 16 + l15], w2v1 = w2[nh * 32 + 16 + l15];

  float v[2][4];
#pragma unroll
  for (int reg = 0; reg < 4; ++reg) {
    float h0 = acc00[reg] + b1v0; h0 = h0 > 0.f ? h0 : 0.f;
    float h1 = acc01[reg] + b1v1; h1 = h1 > 0.f ? h1 : 0.f;
    v[0][reg] = fmaf(h1, w2v1, fmaf(h0, w2v0, 0.f));
    float g0 = acc10[reg] + b1v0; g0 = g0 > 0.f ? g0 : 0.f;
    float g1 = acc11[reg] + b1v1; g1 = g1 > 0.f ? g1 : 0.f;
    v[1][reg] = fmaf(g1, w2v1, fmaf(g0, w2v0, 0.f));
  }
#pragma unroll
  for (int mask = 1; mask < 16; mask <<= 1)
#pragma unroll
    for (int mt = 0; mt < 2; ++mt)
#pragma unroll
      for (int reg = 0; reg < 4; ++reg)
        v[mt][reg] += __shfl_xor(v[mt][reg], mask);

  if (l15 == 0) {
#pragma unroll
    for (int mt = 0; mt < 2; ++mt)
#pragma unroll
      for (int reg = 0; reg < 4; ++reg)
        part[nh][mt * 16 + quad * 4 + reg] = v[mt][reg];
  }
  __syncthreads();
  if (tid < 32)
    logits[m0 + tid] = ((part[0][tid] + part[1][tid]) +
                        (part[2][tid] + part[3][tid])) + b2[0];
}

// ---------------------------------------------------------------------------
// Row kernel: expected_k, k, gumbel, softmax. grid=8, block=1024. (unchanged)
// ---------------------------------------------------------------------------
__global__ __launch_bounds__(1024) void row_kernel(
    const float* __restrict__ logits, const float* __restrict__ u,
    float* __restrict__ soft, int* __restrict__ krow, float* __restrict__ ek_out)
{
  const int b = blockIdx.x;
  const int t = threadIdx.x;
  const float* Lrow = logits + b * S_;
  const float* urow = u + b * S_;

  __shared__ double red[1024];
  __shared__ float  redf[1024];

  float z[4];
  double psig = 0.0;
  float zmax = -INFINITY;
#pragma unroll
  for (int i = 0; i < 4; ++i) {
    int j = t + i * 1024;
    float L = Lrow[j];
    float g = -logf(-logf(urow[j]));
    z[i] = L + g;
    psig += (double)(1.f / (1.f + expf(-L)));
    zmax = fmaxf(zmax, z[i]);
  }
  red[t] = psig; redf[t] = zmax;
  __syncthreads();
  for (int s2 = 512; s2 > 0; s2 >>= 1) {
    if (t < s2) { red[t] += red[t + s2]; redf[t] = fmaxf(redf[t], redf[t + s2]); }
    __syncthreads();
  }
  __shared__ float m_sh; __shared__ double ek_sh;
  if (t == 0) { m_sh = redf[0]; ek_sh = red[0]; }
  __syncthreads();
  float m = m_sh;

  float e[4];
  double pexp = 0.0;
#pragma unroll
  for (int i = 0; i < 4; ++i) { e[i] = expf(z[i] - m); pexp += (double)e[i]; }
  red[t] = pexp;
  __syncthreads();
  for (int s2 = 512; s2 > 0; s2 >>= 1) {
    if (t < s2) red[t] += red[t + s2];
    __syncthreads();
  }
  __shared__ float den_sh;
  if (t == 0) den_sh = (float)red[0];
  __syncthreads();
  float den = den_sh;
#pragma unroll
  for (int i = 0; i < 4; ++i) soft[b * S_ + t + i * 1024] = e[i] / den;

  if (t == 0) {
    float ekf = (float)ek_sh;
    int k = (int)ekf;
    if (k < MIN_K) k = MIN_K;
    krow[b] = k;
    ek_out[b] = ekf;
  }
}

// ---------------------------------------------------------------------------
// Rank partial: grid (16 i-chunks, 4 j-chunks, 8 rows). Integer atomicAdd
// (deterministic). j-chunk staged in LDS; all lanes read same addr (broadcast).
// ---------------------------------------------------------------------------
__global__ __launch_bounds__(256) void rank_kernel(
    const float* __restrict__ soft, int* __restrict__ counts)
{
  __shared__ float4 sjs[256];
  const int b  = blockIdx.z;
  const int ic = blockIdx.x;
  const int jc = blockIdx.y;
  const int tid = threadIdx.x;
  const float* row = soft + b * S_;

  sjs[tid] = ((const float4*)row)[jc * 256 + tid];
  const int i = ic * 256 + tid;
  const float si = row[i];
  __syncthreads();

  int cnt = 0;
  const int jbase = jc * 1024;
  for (int j4 = 0; j4 < 256; ++j4) {
    float4 vv = sjs[j4];
    int j = jbase + j4 * 4;
    cnt += (vv.x > si) || (vv.x == si && (j + 0) < i);
    cnt += (vv.y > si) || (vv.y == si && (j + 1) < i);
    cnt += (vv.z > si) || (vv.z == si && (j + 2) < i);
    cnt += (vv.w > si) || (vv.w == si && (j + 3) < i);
  }
  atomicAdd(&counts[b * S_ + i], cnt);
}

// ---------------------------------------------------------------------------
// Filter + mask finalize: one block per token (1024 floats). Uniform scalar
// loads of cnt/k/soft; thread 0 writes selection_mask.
// ---------------------------------------------------------------------------
__global__ __launch_bounds__(256) void filter_kernel(
    const float* __restrict__ x, const float* __restrict__ soft,
    const int* __restrict__ counts, const int* __restrict__ krow,
    float* __restrict__ out, float* __restrict__ mask_out)
{
  const int token = blockIdx.x;           // 0..32767
  const int b = token >> 12;              // S_=4096
  const float s = soft[token];
  const float h = (counts[token] < krow[b]) ? 1.f : 0.f;
  const float sel = (h - s) + s;

  size_t base = (size_t)token * (E_ / 4) + threadIdx.x;
  float4 v = ((const float4*)x)[base];
  v.x *= sel; v.y *= sel; v.z *= sel; v.w *= sel;
  ((float4*)out)[base] = v;
  if (threadIdx.x == 0) mask_out[token] = sel;
}

// ---------------------------------------------------------------------------
extern "C" void kernel_launch(void* const* d_in, const int* in_sizes, int n_in,
                              void* d_out, int out_size, void* d_ws, size_t ws_size,
                              hipStream_t stream) {
  const float* x  = (const float*)d_in[0];
  const float* w1 = (const float*)d_in[1];
  const float* b1 = (const float*)d_in[2];
  const float* w2 = (const float*)d_in[3];
  const float* b2 = (const float*)d_in[4];
  const float* u  = (const float*)d_in[5];

  float* out = (float*)d_out;
  float* out_filt = out;
  float* out_mask = out + OUT_MASK_OFF;
  float* out_ek   = out + OUT_EK_OFF;

  char* ws = (char*)d_ws;
  float*          ws_logits = (float*)(ws + LOGITS_OFF);
  float*          ws_soft   = (float*)(ws + SOFT_OFF);
  int*            ws_cnt    = (int*)(ws + CNT_OFF);
  int*            ws_krow   = (int*)(ws + KROW_OFF);
  unsigned short* ws_w1thi  = (unsigned short*)(ws + W1T_HI_OFF);
  unsigned short* ws_w1tlo  = (unsigned short*)(ws + W1T_LO_OFF);

  hipMemsetAsync(ws_cnt, 0, B_ * S_ * sizeof(int), stream);
  prep_w_kernel<<<dim3(128), dim3(256), 0, stream>>>(w1, ws_w1thi, ws_w1tlo);
  scorer_kernel<<<dim3(B_ * S_ / 32), dim3(256), 0, stream>>>(
      x, ws_w1thi, ws_w1tlo, b1, w2, b2, ws_logits);
  row_kernel<<<dim3(B_), dim3(1024), 0, stream>>>(ws_logits, u, ws_soft, ws_krow, out_ek);
  rank_kernel<<<dim3(16, 4, 8), dim3(256), 0, stream>>>(ws_soft, ws_cnt);
  filter_kernel<<<dim3(B_ * S_), dim3(256), 0, stream>>>(
      x, ws_soft, ws_cnt, ws_krow, out_filt, out_mask);
}

// Round 5
// 313.773 us; speedup vs baseline: 1.2484x; 1.2484x over previous
//
#include <hip/hip_runtime.h>
#include <hip/hip_bf16.h>
#include <math.h>

// Problem constants
#define B_ 8
#define S_ 4096
#define E_ 1024
#define H_ 128
#define MIN_K 32
// d_out layout: filtered [B,S,E] | selection_mask [B,S] | expected_k [B]
#define OUT_MASK_OFF (B_*S_*E_)
#define OUT_EK_OFF   (B_*S_*E_ + B_*S_)

// workspace byte offsets (total 917,536 B)
#define LOGITS_OFF 0
#define SOFT_OFF   131072
#define CNT_OFF    262144
#define KROW_OFF   393216
#define WB_OFF     393248   // 16B aligned; 512 KB tiled split-bf16 weights

typedef __attribute__((ext_vector_type(8))) short   frag8;   // 8 bf16 (4 VGPR)
typedef __attribute__((ext_vector_type(4))) float   fragc;   // 4 f32 acc

static __device__ __forceinline__ unsigned short bf16_rne(float f) {
  unsigned u = __float_as_uint(f);
  unsigned r = u + 0x7FFF + ((u >> 16) & 1);
  return (unsigned short)(r >> 16);
}
static __device__ __forceinline__ float bf16_to_f32(unsigned short h) {
  return __uint_as_float(((unsigned)h) << 16);
}

// ---------------------------------------------------------------------------
// Prep: w1 [E][H] f32 -> wb tiled split-bf16:
//   wb[t][plane][n][k']  t=k-tile (32 tiles of KT=32), plane 0=hi 1=lo,
//   n=0..127, k'=0..31.  Each per-K-step B chunk = 16 KB CONTIGUOUS, so the
//   scorer's staging load is a flat coalesced copy (1 line per 4 lanes).
// ---------------------------------------------------------------------------
__global__ __launch_bounds__(256) void prep_w_kernel(
    const float* __restrict__ w1, unsigned short* __restrict__ wb)
{
  int id = blockIdx.x * 256 + threadIdx.x;       // 0..32767
  int k  = id >> 5;                               // 0..1023
  int n4 = id & 31;                               // 0..31
  float4 w = *(const float4*)(w1 + k * H_ + n4 * 4);
  int t  = k >> 5;          // k-tile
  int kp = k & 31;          // k'
#pragma unroll
  for (int e = 0; e < 4; ++e) {
    float f = (e == 0) ? w.x : (e == 1) ? w.y : (e == 2) ? w.z : w.w;
    unsigned short hi = bf16_rne(f);
    unsigned short lo = bf16_rne(f - bf16_to_f32(hi));
    int n = n4 * 4 + e;
    wb[t * 8192 +        n * 32 + kp] = hi;   // plane 0
    wb[t * 8192 + 4096 + n * 32 + kp] = lo;   // plane 1
  }
}

// ---------------------------------------------------------------------------
// Scorer v5: line-count-minimal. Model from v1..v4 post-mortems: scorer time
// ~= per-CU 64B-line transactions x ~5.6 cy (scattered fragment loads emit 16
// lines/instr; v1 33k lines -> 187k cy, v4 65k -> 360k cy). Fix: fetch each
// byte exactly once per block and only coalesced:
//   M=128 rows/block, grid 256 = 1 block/CU, 512 thr (8 waves, 4mg x 2ng).
//   Per block: A = 512 KB (x, coalesced reg-stage + convert), B = 512 KB
//   (wb tiled chunks, flat copy) -> 16.4k lines/CU (2x less than v1).
//   LDS: padded stride 40 (v1-proven), double-buffered, 1 barrier/step,
//   next-tile loads issued before compute (2-phase pattern).
// Wave w: mg=w>>1 rows [mg*32,+32), ng=w&1 cols [ng*64,+64); 24 MFMA/step.
// ---------------------------------------------------------------------------
#define KT 32
#define NTILES (E_ / KT)
#define XS 40   // padded LDS stride in shorts (80 B)

__global__ __launch_bounds__(512, 2) void scorer_kernel(
    const float* __restrict__ x,
    const unsigned short* __restrict__ wb,
    const float* __restrict__ b1, const float* __restrict__ w2,
    const float* __restrict__ b2, float* __restrict__ logits)
{
  __shared__ unsigned short as_hi[2][128 * XS];
  __shared__ unsigned short as_lo[2][128 * XS];
  __shared__ unsigned short bs_hi[2][128 * XS];
  __shared__ unsigned short bs_lo[2][128 * XS];
  __shared__ float part[2][128];

  const int tid  = threadIdx.x;
  const int wv   = tid >> 6;
  const int lane = tid & 63;
  const int l15  = lane & 15;
  const int quad = lane >> 4;
  const int mg   = wv >> 1;          // m-group: rows [mg*32, +32)
  const int ng   = wv & 1;           // n-group: cols [ng*64, +64)
  const int m0   = blockIdx.x * 128;

  // A staging map: thread -> (row r, part p): 8 consecutive floats of row r.
  const int r = tid >> 2, p = tid & 3;
  const float* __restrict__ xsrc = x + (size_t)(m0 + r) * E_ + p * 8;
  // B staging map: flat copy; tid*16 shorts decomposes as plane|n|half.
  const unsigned short* __restrict__ bsrc = wb + tid * 16;
  const int bplane = tid >> 8;              // wave-uniform
  const int boff   = ((tid >> 1) & 127) * XS + (tid & 1) * 16;
  const int aoff   = r * XS + p * 8;

  fragc acc[2][4];
#pragma unroll
  for (int mt = 0; mt < 2; ++mt)
#pragma unroll
    for (int nt = 0; nt < 4; ++nt)
      acc[mt][nt] = (fragc)(0.f);

  // ---- prologue: tile 0 ----
  float4 a0 = *(const float4*)(xsrc);
  float4 a1 = *(const float4*)(xsrc + 4);
  uint4  q0 = *(const uint4*)(bsrc);
  uint4  q1 = *(const uint4*)(bsrc + 8);
  {
    frag8 h8, l8;
    float f[8] = {a0.x, a0.y, a0.z, a0.w, a1.x, a1.y, a1.z, a1.w};
#pragma unroll
    for (int e = 0; e < 8; ++e) {
      unsigned short hi = bf16_rne(f[e]);
      h8[e] = (short)hi; l8[e] = (short)bf16_rne(f[e] - bf16_to_f32(hi));
    }
    *(frag8*)&as_hi[0][aoff] = h8;
    *(frag8*)&as_lo[0][aoff] = l8;
    unsigned short* bd = bplane ? &bs_lo[0][boff] : &bs_hi[0][boff];
    *(uint4*)(bd) = q0;
    *(uint4*)(bd + 8) = q1;
  }
  __syncthreads();

#pragma unroll 1
  for (int t = 0; t < NTILES; ++t) {
    const int buf = t & 1;
    const bool more = (t + 1 < NTILES);

    // issue next-tile loads first (latency hides under compute)
    float4 na0, na1; uint4 nq0, nq1;
    if (more) {
      na0 = *(const float4*)(xsrc + (t + 1) * KT);
      na1 = *(const float4*)(xsrc + (t + 1) * KT + 4);
      nq0 = *(const uint4*)(bsrc + (t + 1) * 8192);
      nq1 = *(const uint4*)(bsrc + (t + 1) * 8192 + 8);
    }

    // fragments from LDS buf
    frag8 ah[2], al[2], bh[4], bl[4];
#pragma unroll
    for (int mt = 0; mt < 2; ++mt) {
      int a = (mg * 32 + mt * 16 + l15) * XS + quad * 8;
      ah[mt] = *(const frag8*)&as_hi[buf][a];
      al[mt] = *(const frag8*)&as_lo[buf][a];
    }
#pragma unroll
    for (int nt = 0; nt < 4; ++nt) {
      int a = (ng * 64 + nt * 16 + l15) * XS + quad * 8;
      bh[nt] = *(const frag8*)&bs_hi[buf][a];
      bl[nt] = *(const frag8*)&bs_lo[buf][a];
    }

    // 24 MFMAs; per-acc chain order: hh, hl, lh (v1 numerics)
#pragma unroll
    for (int mt = 0; mt < 2; ++mt)
#pragma unroll
      for (int nt = 0; nt < 4; ++nt) {
        acc[mt][nt] = __builtin_amdgcn_mfma_f32_16x16x32_bf16(ah[mt], bh[nt], acc[mt][nt], 0, 0, 0);
        acc[mt][nt] = __builtin_amdgcn_mfma_f32_16x16x32_bf16(ah[mt], bl[nt], acc[mt][nt], 0, 0, 0);
        acc[mt][nt] = __builtin_amdgcn_mfma_f32_16x16x32_bf16(al[mt], bh[nt], acc[mt][nt], 0, 0, 0);
      }

    // convert + write next tile into buf^1
    if (more) {
      frag8 h8, l8;
      float f[8] = {na0.x, na0.y, na0.z, na0.w, na1.x, na1.y, na1.z, na1.w};
#pragma unroll
      for (int e = 0; e < 8; ++e) {
        unsigned short hi = bf16_rne(f[e]);
        h8[e] = (short)hi; l8[e] = (short)bf16_rne(f[e] - bf16_to_f32(hi));
      }
      *(frag8*)&as_hi[buf ^ 1][aoff] = h8;
      *(frag8*)&as_lo[buf ^ 1][aoff] = l8;
      unsigned short* bd = bplane ? &bs_lo[buf ^ 1][boff] : &bs_hi[buf ^ 1][boff];
      *(uint4*)(bd) = nq0;
      *(uint4*)(bd + 8) = nq1;
    }
    __syncthreads();
  }

  // Epilogue: h = relu(acc + b1[n]); p = sum_nt h*w2[n] (ascending fmaf);
  // 16-lane butterfly (n); cross ng-groups via LDS.
  float b1v[4], w2v[4];
#pragma unroll
  for (int nt = 0; nt < 4; ++nt) {
    int n = ng * 64 + nt * 16 + l15;
    b1v[nt] = b1[n]; w2v[nt] = w2[n];
  }
  float v[2][4];
#pragma unroll
  for (int mt = 0; mt < 2; ++mt)
#pragma unroll
    for (int reg = 0; reg < 4; ++reg) {
      float pacc = 0.f;
#pragma unroll
      for (int nt = 0; nt < 4; ++nt) {
        float h = acc[mt][nt][reg] + b1v[nt];
        h = h > 0.f ? h : 0.f;
        pacc = fmaf(h, w2v[nt], pacc);
      }
      v[mt][reg] = pacc;
    }
#pragma unroll
  for (int mask = 1; mask < 16; mask <<= 1)
#pragma unroll
    for (int mt = 0; mt < 2; ++mt)
#pragma unroll
      for (int reg = 0; reg < 4; ++reg)
        v[mt][reg] += __shfl_xor(v[mt][reg], mask);

  if (l15 == 0) {
#pragma unroll
    for (int mt = 0; mt < 2; ++mt)
#pragma unroll
      for (int reg = 0; reg < 4; ++reg)
        part[ng][mg * 32 + mt * 16 + quad * 4 + reg] = v[mt][reg];
  }
  __syncthreads();
  if (tid < 128)
    logits[m0 + tid] = (part[0][tid] + part[1][tid]) + b2[0];
}

// ---------------------------------------------------------------------------
// Row kernel: expected_k, k, gumbel, softmax. grid=8, block=1024. (unchanged)
// ---------------------------------------------------------------------------
__global__ __launch_bounds__(1024) void row_kernel(
    const float* __restrict__ logits, const float* __restrict__ u,
    float* __restrict__ soft, int* __restrict__ krow, float* __restrict__ ek_out)
{
  const int b = blockIdx.x;
  const int t = threadIdx.x;
  const float* Lrow = logits + b * S_;
  const float* urow = u + b * S_;

  __shared__ double red[1024];
  __shared__ float  redf[1024];

  float z[4];
  double psig = 0.0;
  float zmax = -INFINITY;
#pragma unroll
  for (int i = 0; i < 4; ++i) {
    int j = t + i * 1024;
    float L = Lrow[j];
    float g = -logf(-logf(urow[j]));
    z[i] = L + g;
    psig += (double)(1.f / (1.f + expf(-L)));
    zmax = fmaxf(zmax, z[i]);
  }
  red[t] = psig; redf[t] = zmax;
  __syncthreads();
  for (int s2 = 512; s2 > 0; s2 >>= 1) {
    if (t < s2) { red[t] += red[t + s2]; redf[t] = fmaxf(redf[t], redf[t + s2]); }
    __syncthreads();
  }
  __shared__ float m_sh; __shared__ double ek_sh;
  if (t == 0) { m_sh = redf[0]; ek_sh = red[0]; }
  __syncthreads();
  float m = m_sh;

  float e[4];
  double pexp = 0.0;
#pragma unroll
  for (int i = 0; i < 4; ++i) { e[i] = expf(z[i] - m); pexp += (double)e[i]; }
  red[t] = pexp;
  __syncthreads();
  for (int s2 = 512; s2 > 0; s2 >>= 1) {
    if (t < s2) red[t] += red[t + s2];
    __syncthreads();
  }
  __shared__ float den_sh;
  if (t == 0) den_sh = (float)red[0];
  __syncthreads();
  float den = den_sh;
#pragma unroll
  for (int i = 0; i < 4; ++i) soft[b * S_ + t + i * 1024] = e[i] / den;

  if (t == 0) {
    float ekf = (float)ek_sh;
    int k = (int)ekf;
    if (k < MIN_K) k = MIN_K;
    krow[b] = k;
    ek_out[b] = ekf;
  }
}

// ---------------------------------------------------------------------------
// Rank partial: grid (16 i-chunks, 4 j-chunks, 8 rows). Integer atomicAdd
// (deterministic). j-chunk staged in LDS; all lanes read same addr (broadcast).
// ---------------------------------------------------------------------------
__global__ __launch_bounds__(256) void rank_kernel(
    const float* __restrict__ soft, int* __restrict__ counts)
{
  __shared__ float4 sjs[256];
  const int b  = blockIdx.z;
  const int ic = blockIdx.x;
  const int jc = blockIdx.y;
  const int tid = threadIdx.x;
  const float* row = soft + b * S_;

  sjs[tid] = ((const float4*)row)[jc * 256 + tid];
  const int i = ic * 256 + tid;
  const float si = row[i];
  __syncthreads();

  int cnt = 0;
  const int jbase = jc * 1024;
  for (int j4 = 0; j4 < 256; ++j4) {
    float4 vv = sjs[j4];
    int j = jbase + j4 * 4;
    cnt += (vv.x > si) || (vv.x == si && (j + 0) < i);
    cnt += (vv.y > si) || (vv.y == si && (j + 1) < i);
    cnt += (vv.z > si) || (vv.z == si && (j + 2) < i);
    cnt += (vv.w > si) || (vv.w == si && (j + 3) < i);
  }
  atomicAdd(&counts[b * S_ + i], cnt);
}

// ---------------------------------------------------------------------------
// Filter + mask finalize: one block per token (1024 floats). Uniform scalar
// loads of cnt/k/soft; thread 0 writes selection_mask.
// ---------------------------------------------------------------------------
__global__ __launch_bounds__(256) void filter_kernel(
    const float* __restrict__ x, const float* __restrict__ soft,
    const int* __restrict__ counts, const int* __restrict__ krow,
    float* __restrict__ out, float* __restrict__ mask_out)
{
  const int token = blockIdx.x;           // 0..32767
  const int b = token >> 12;              // S_=4096
  const float s = soft[token];
  const float h = (counts[token] < krow[b]) ? 1.f : 0.f;
  const float sel = (h - s) + s;

  size_t base = (size_t)token * (E_ / 4) + threadIdx.x;
  float4 v = ((const float4*)x)[base];
  v.x *= sel; v.y *= sel; v.z *= sel; v.w *= sel;
  ((float4*)out)[base] = v;
  if (threadIdx.x == 0) mask_out[token] = sel;
}

// ---------------------------------------------------------------------------
extern "C" void kernel_launch(void* const* d_in, const int* in_sizes, int n_in,
                              void* d_out, int out_size, void* d_ws, size_t ws_size,
                              hipStream_t stream) {
  const float* x  = (const float*)d_in[0];
  const float* w1 = (const float*)d_in[1];
  const float* b1 = (const float*)d_in[2];
  const float* w2 = (const float*)d_in[3];
  const float* b2 = (const float*)d_in[4];
  const float* u  = (const float*)d_in[5];

  float* out = (float*)d_out;
  float* out_filt = out;
  float* out_mask = out + OUT_MASK_OFF;
  float* out_ek   = out + OUT_EK_OFF;

  char* ws = (char*)d_ws;
  float*          ws_logits = (float*)(ws + LOGITS_OFF);
  float*          ws_soft   = (float*)(ws + SOFT_OFF);
  int*            ws_cnt    = (int*)(ws + CNT_OFF);
  int*            ws_krow   = (int*)(ws + KROW_OFF);
  unsigned short* ws_wb     = (unsigned short*)(ws + WB_OFF);

  hipMemsetAsync(ws_cnt, 0, B_ * S_ * sizeof(int), stream);
  prep_w_kernel<<<dim3(128), dim3(256), 0, stream>>>(w1, ws_wb);
  scorer_kernel<<<dim3(B_ * S_ / 128), dim3(512), 0, stream>>>(
      x, ws_wb, b1, w2, b2, ws_logits);
  row_kernel<<<dim3(B_), dim3(1024), 0, stream>>>(ws_logits, u, ws_soft, ws_krow, out_ek);
  rank_kernel<<<dim3(16, 4, 8), dim3(256), 0, stream>>>(ws_soft, ws_cnt);
  filter_kernel<<<dim3(B_ * S_), dim3(256), 0, stream>>>(
      x, ws_soft, ws_cnt, ws_krow, out_filt, out_mask);
}

// Round 6
// 311.610 us; speedup vs baseline: 1.2571x; 1.0069x over previous
//
#include <hip/hip_runtime.h>
#include <hip/hip_bf16.h>
#include <math.h>

// Problem constants
#define B_ 8
#define S_ 4096
#define E_ 1024
#define H_ 128
#define MIN_K 32
// d_out layout: filtered [B,S,E] | selection_mask [B,S] | expected_k [B]
#define OUT_MASK_OFF (B_*S_*E_)
#define OUT_EK_OFF   (B_*S_*E_ + B_*S_)

// workspace byte offsets (total 917,536 B)
#define LOGITS_OFF 0
#define SOFT_OFF   131072
#define CNT_OFF    262144
#define KROW_OFF   393216
#define WB_OFF     393248   // 16B aligned; 512 KB tiled split-bf16 weights

typedef __attribute__((ext_vector_type(8))) short   frag8;   // 8 bf16 (4 VGPR)
typedef __attribute__((ext_vector_type(4))) float   fragc;   // 4 f32 acc

static __device__ __forceinline__ unsigned short bf16_rne(float f) {
  unsigned u = __float_as_uint(f);
  unsigned r = u + 0x7FFF + ((u >> 16) & 1);
  return (unsigned short)(r >> 16);
}
static __device__ __forceinline__ float bf16_to_f32(unsigned short h) {
  return __uint_as_float(((unsigned)h) << 16);
}

// ---------------------------------------------------------------------------
// Prep: w1 [E][H] f32 -> wb tiled split-bf16:
//   wb[t][plane][n][k']  t=k-tile (32 tiles of KT=32), plane 0=hi 1=lo,
//   n=0..127, k'=0..31.  Each per-K-step B chunk = 16 KB CONTIGUOUS, so the
//   scorer's staging load is a flat coalesced copy (1 line per 4 lanes).
// ---------------------------------------------------------------------------
__global__ __launch_bounds__(256) void prep_w_kernel(
    const float* __restrict__ w1, unsigned short* __restrict__ wb)
{
  int id = blockIdx.x * 256 + threadIdx.x;       // 0..32767
  int k  = id >> 5;                               // 0..1023
  int n4 = id & 31;                               // 0..31
  float4 w = *(const float4*)(w1 + k * H_ + n4 * 4);
  int t  = k >> 5;          // k-tile
  int kp = k & 31;          // k'
#pragma unroll
  for (int e = 0; e < 4; ++e) {
    float f = (e == 0) ? w.x : (e == 1) ? w.y : (e == 2) ? w.z : w.w;
    unsigned short hi = bf16_rne(f);
    unsigned short lo = bf16_rne(f - bf16_to_f32(hi));
    int n = n4 * 4 + e;
    wb[t * 8192 +        n * 32 + kp] = hi;   // plane 0
    wb[t * 8192 + 4096 + n * 32 + kp] = lo;   // plane 1
  }
}

// ---------------------------------------------------------------------------
// Scorer v6: 2-deep stage pipeline. v5 post-mortem: step 5.5k cy vs 2.9k
// VMEM-service floor — loads for t+1 issued at step-t top can't be serviced
// within one compute window, so the wait before convert+ds_write stalls ~2k
// cy/step. Fix:
//  (a) depth-2: named register sets S0/S1 (manual unroll x2, static names);
//      phase top issues loads for t+2, ds_write stores t+1's regs (loaded a
//      FULL step ago -> counted vmcnt, t+2 loads stay in flight across the
//      barrier). sched_barrier(0) after each load cluster pins vs sinking.
//  (b) A staged as raw f32 (same 16 KB/tile, same ds_read count); split-bf16
//      convert AFTER the LDS read (off the load->write critical path; VALU
//      hides under MFMA). Identical hi/lo bits -> numerics unchanged from v5.
// Geometry unchanged: M=128/block, grid 256 (1 block/CU), 512 thr, 8 waves
// (4 mg x 2 ng), 24 MFMA/wave/step, each global byte fetched once per block.
// ---------------------------------------------------------------------------
#define KT 32
#define NTILES (E_ / KT)
#define AS 36   // A LDS stride in floats (144 B: 16B-aligned, 2-way banks = free)
#define XS 40   // B LDS stride in shorts (80 B)

#define ISSUE_LOADS(Sa0, Sa1, Sq0, Sq1, T)                  \
    Sa0 = *(const float4*)(xsrc + (T) * KT);                \
    Sa1 = *(const float4*)(xsrc + (T) * KT + 4);            \
    Sq0 = *(const uint4*)(bsrc + (T) * 8192);               \
    Sq1 = *(const uint4*)(bsrc + (T) * 8192 + 8);

#define WRITE_STAGE(BUF, Sa0, Sa1, Sq0, Sq1) {              \
    *(float4*)&as_f[BUF][aoff]     = Sa0;                   \
    *(float4*)&as_f[BUF][aoff + 4] = Sa1;                   \
    unsigned short* bd_ = bplane ? &bs_lo[BUF][boff]        \
                                 : &bs_hi[BUF][boff];       \
    *(uint4*)(bd_)     = Sq0;                               \
    *(uint4*)(bd_ + 8) = Sq1; }

#define COMPUTE(BUF) {                                                        \
    frag8 ah[2], al[2], bh[4], bl[4];                                         \
    _Pragma("unroll") for (int mt = 0; mt < 2; ++mt) {                        \
      int a_ = (mg * 32 + mt * 16 + l15) * AS + quad * 8;                     \
      float4 f0_ = *(const float4*)&as_f[BUF][a_];                            \
      float4 f1_ = *(const float4*)&as_f[BUF][a_ + 4];                        \
      float ff_[8] = {f0_.x, f0_.y, f0_.z, f0_.w, f1_.x, f1_.y, f1_.z, f1_.w};\
      _Pragma("unroll") for (int e = 0; e < 8; ++e) {                         \
        unsigned short hi_ = bf16_rne(ff_[e]);                                \
        ah[mt][e] = (short)hi_;                                               \
        al[mt][e] = (short)bf16_rne(ff_[e] - bf16_to_f32(hi_)); } }           \
    _Pragma("unroll") for (int nt = 0; nt < 4; ++nt) {                        \
      int a_ = (ng * 64 + nt * 16 + l15) * XS + quad * 8;                     \
      bh[nt] = *(const frag8*)&bs_hi[BUF][a_];                                \
      bl[nt] = *(const frag8*)&bs_lo[BUF][a_]; }                              \
    _Pragma("unroll") for (int mt = 0; mt < 2; ++mt)                          \
      _Pragma("unroll") for (int nt = 0; nt < 4; ++nt) {                      \
        acc[mt][nt] = __builtin_amdgcn_mfma_f32_16x16x32_bf16(ah[mt], bh[nt], acc[mt][nt], 0, 0, 0); \
        acc[mt][nt] = __builtin_amdgcn_mfma_f32_16x16x32_bf16(ah[mt], bl[nt], acc[mt][nt], 0, 0, 0); \
        acc[mt][nt] = __builtin_amdgcn_mfma_f32_16x16x32_bf16(al[mt], bh[nt], acc[mt][nt], 0, 0, 0); } }

__global__ __launch_bounds__(512, 2) void scorer_kernel(
    const float* __restrict__ x,
    const unsigned short* __restrict__ wb,
    const float* __restrict__ b1, const float* __restrict__ w2,
    const float* __restrict__ b2, float* __restrict__ logits)
{
  __shared__ float          as_f[2][128 * AS];
  __shared__ unsigned short bs_hi[2][128 * XS];
  __shared__ unsigned short bs_lo[2][128 * XS];
  __shared__ float part[2][128];

  const int tid  = threadIdx.x;
  const int wv   = tid >> 6;
  const int lane = tid & 63;
  const int l15  = lane & 15;
  const int quad = lane >> 4;
  const int mg   = wv >> 1;          // m-group: rows [mg*32, +32)
  const int ng   = wv & 1;           // n-group: cols [ng*64, +64)
  const int m0   = blockIdx.x * 128;

  // A staging map: thread -> (row r, part p): 8 consecutive floats of row r.
  const int r = tid >> 2, p = tid & 3;
  const float* __restrict__ xsrc = x + (size_t)(m0 + r) * E_ + p * 8;
  // B staging map: flat copy; tid*16 shorts decomposes as plane|n|half.
  const unsigned short* __restrict__ bsrc = wb + tid * 16;
  const int bplane = tid >> 8;              // wave-uniform
  const int boff   = ((tid >> 1) & 127) * XS + (tid & 1) * 16;
  const int aoff   = r * AS + p * 8;        // floats

  fragc acc[2][4];
#pragma unroll
  for (int mt = 0; mt < 2; ++mt)
#pragma unroll
    for (int nt = 0; nt < 4; ++nt)
      acc[mt][nt] = (fragc)(0.f);

  // named stage register sets (rule #20: static, never runtime-indexed)
  float4 a0_S0, a1_S0; uint4 q0_S0, q1_S0;
  float4 a0_S1, a1_S1; uint4 q0_S1, q1_S1;

  // ---- prologue: S0 <- tile0, S1 <- tile1, write S0 -> buf0 ----
  ISSUE_LOADS(a0_S0, a1_S0, q0_S0, q1_S0, 0)
  ISSUE_LOADS(a0_S1, a1_S1, q0_S1, q1_S1, 1)
  WRITE_STAGE(0, a0_S0, a1_S0, q0_S0, q1_S0)
  __syncthreads();

  // invariant at top of phase computing tile t (buf t&1): regs for t+1 held;
  // issue loads for t+2 now; write t+1 after compute; barrier.
  for (int tp = 0; tp < 16; ++tp) {
    const bool more = (tp < 15);
    // EVEN phase: tile 2tp from buf0; S1 holds 2tp+1; S0 <- 2tp+2
    if (more) { ISSUE_LOADS(a0_S0, a1_S0, q0_S0, q1_S0, 2 * tp + 2) }
    __builtin_amdgcn_sched_barrier(0);
    COMPUTE(0)
    WRITE_STAGE(1, a0_S1, a1_S1, q0_S1, q1_S1)
    __syncthreads();
    // ODD phase: tile 2tp+1 from buf1; S0 holds 2tp+2; S1 <- 2tp+3
    if (more) { ISSUE_LOADS(a0_S1, a1_S1, q0_S1, q1_S1, 2 * tp + 3) }
    __builtin_amdgcn_sched_barrier(0);
    COMPUTE(1)
    if (more) { WRITE_STAGE(0, a0_S0, a1_S0, q0_S0, q1_S0) }
    __syncthreads();
  }

  // Epilogue (v5's exact tree): h = relu(acc + b1[n]); p = sum_nt h*w2[n]
  // (ascending fmaf); 16-lane butterfly (n); cross ng-groups via LDS.
  float b1v[4], w2v[4];
#pragma unroll
  for (int nt = 0; nt < 4; ++nt) {
    int n = ng * 64 + nt * 16 + l15;
    b1v[nt] = b1[n]; w2v[nt] = w2[n];
  }
  float v[2][4];
#pragma unroll
  for (int mt = 0; mt < 2; ++mt)
#pragma unroll
    for (int reg = 0; reg < 4; ++reg) {
      float pacc = 0.f;
#pragma unroll
      for (int nt = 0; nt < 4; ++nt) {
        float h = acc[mt][nt][reg] + b1v[nt];
        h = h > 0.f ? h : 0.f;
        pacc = fmaf(h, w2v[nt], pacc);
      }
      v[mt][reg] = pacc;
    }
#pragma unroll
  for (int mask = 1; mask < 16; mask <<= 1)
#pragma unroll
    for (int mt = 0; mt < 2; ++mt)
#pragma unroll
      for (int reg = 0; reg < 4; ++reg)
        v[mt][reg] += __shfl_xor(v[mt][reg], mask);

  if (l15 == 0) {
#pragma unroll
    for (int mt = 0; mt < 2; ++mt)
#pragma unroll
      for (int reg = 0; reg < 4; ++reg)
        part[ng][mg * 32 + mt * 16 + quad * 4 + reg] = v[mt][reg];
  }
  __syncthreads();
  if (tid < 128)
    logits[m0 + tid] = (part[0][tid] + part[1][tid]) + b2[0];
}

// ---------------------------------------------------------------------------
// Row kernel: expected_k, k, gumbel, softmax. grid=8, block=1024. (unchanged)
// ---------------------------------------------------------------------------
__global__ __launch_bounds__(1024) void row_kernel(
    const float* __restrict__ logits, const float* __restrict__ u,
    float* __restrict__ soft, int* __restrict__ krow, float* __restrict__ ek_out)
{
  const int b = blockIdx.x;
  const int t = threadIdx.x;
  const float* Lrow = logits + b * S_;
  const float* urow = u + b * S_;

  __shared__ double red[1024];
  __shared__ float  redf[1024];

  float z[4];
  double psig = 0.0;
  float zmax = -INFINITY;
#pragma unroll
  for (int i = 0; i < 4; ++i) {
    int j = t + i * 1024;
    float L = Lrow[j];
    float g = -logf(-logf(urow[j]));
    z[i] = L + g;
    psig += (double)(1.f / (1.f + expf(-L)));
    zmax = fmaxf(zmax, z[i]);
  }
  red[t] = psig; redf[t] = zmax;
  __syncthreads();
  for (int s2 = 512; s2 > 0; s2 >>= 1) {
    if (t < s2) { red[t] += red[t + s2]; redf[t] = fmaxf(redf[t], redf[t + s2]); }
    __syncthreads();
  }
  __shared__ float m_sh; __shared__ double ek_sh;
  if (t == 0) { m_sh = redf[0]; ek_sh = red[0]; }
  __syncthreads();
  float m = m_sh;

  float e[4];
  double pexp = 0.0;
#pragma unroll
  for (int i = 0; i < 4; ++i) { e[i] = expf(z[i] - m); pexp += (double)e[i]; }
  red[t] = pexp;
  __syncthreads();
  for (int s2 = 512; s2 > 0; s2 >>= 1) {
    if (t < s2) red[t] += red[t + s2];
    __syncthreads();
  }
  __shared__ float den_sh;
  if (t == 0) den_sh = (float)red[0];
  __syncthreads();
  float den = den_sh;
#pragma unroll
  for (int i = 0; i < 4; ++i) soft[b * S_ + t + i * 1024] = e[i] / den;

  if (t == 0) {
    float ekf = (float)ek_sh;
    int k = (int)ekf;
    if (k < MIN_K) k = MIN_K;
    krow[b] = k;
    ek_out[b] = ekf;
  }
}

// ---------------------------------------------------------------------------
// Rank partial: grid (16 i-chunks, 4 j-chunks, 8 rows). Integer atomicAdd
// (deterministic). j-chunk staged in LDS; all lanes read same addr (broadcast).
// ---------------------------------------------------------------------------
__global__ __launch_bounds__(256) void rank_kernel(
    const float* __restrict__ soft, int* __restrict__ counts)
{
  __shared__ float4 sjs[256];
  const int b  = blockIdx.z;
  const int ic = blockIdx.x;
  const int jc = blockIdx.y;
  const int tid = threadIdx.x;
  const float* row = soft + b * S_;

  sjs[tid] = ((const float4*)row)[jc * 256 + tid];
  const int i = ic * 256 + tid;
  const float si = row[i];
  __syncthreads();

  int cnt = 0;
  const int jbase = jc * 1024;
  for (int j4 = 0; j4 < 256; ++j4) {
    float4 vv = sjs[j4];
    int j = jbase + j4 * 4;
    cnt += (vv.x > si) || (vv.x == si && (j + 0) < i);
    cnt += (vv.y > si) || (vv.y == si && (j + 1) < i);
    cnt += (vv.z > si) || (vv.z == si && (j + 2) < i);
    cnt += (vv.w > si) || (vv.w == si && (j + 3) < i);
  }
  atomicAdd(&counts[b * S_ + i], cnt);
}

// ---------------------------------------------------------------------------
// Filter + mask finalize: one block per token (1024 floats). Uniform scalar
// loads of cnt/k/soft; thread 0 writes selection_mask.
// ---------------------------------------------------------------------------
__global__ __launch_bounds__(256) void filter_kernel(
    const float* __restrict__ x, const float* __restrict__ soft,
    const int* __restrict__ counts, const int* __restrict__ krow,
    float* __restrict__ out, float* __restrict__ mask_out)
{
  const int token = blockIdx.x;           // 0..32767
  const int b = token >> 12;              // S_=4096
  const float s = soft[token];
  const float h = (counts[token] < krow[b]) ? 1.f : 0.f;
  const float sel = (h - s) + s;

  size_t base = (size_t)token * (E_ / 4) + threadIdx.x;
  float4 v = ((const float4*)x)[base];
  v.x *= sel; v.y *= sel; v.z *= sel; v.w *= sel;
  ((float4*)out)[base] = v;
  if (threadIdx.x == 0) mask_out[token] = sel;
}

// ---------------------------------------------------------------------------
extern "C" void kernel_launch(void* const* d_in, const int* in_sizes, int n_in,
                              void* d_out, int out_size, void* d_ws, size_t ws_size,
                              hipStream_t stream) {
  const float* x  = (const float*)d_in[0];
  const float* w1 = (const float*)d_in[1];
  const float* b1 = (const float*)d_in[2];
  const float* w2 = (const float*)d_in[3];
  const float* b2 = (const float*)d_in[4];
  const float* u  = (const float*)d_in[5];

  float* out = (float*)d_out;
  float* out_filt = out;
  float* out_mask = out + OUT_MASK_OFF;
  float* out_ek   = out + OUT_EK_OFF;

  char* ws = (char*)d_ws;
  float*          ws_logits = (float*)(ws + LOGITS_OFF);
  float*          ws_soft   = (float*)(ws + SOFT_OFF);
  int*            ws_cnt    = (int*)(ws + CNT_OFF);
  int*            ws_krow   = (int*)(ws + KROW_OFF);
  unsigned short* ws_wb     = (unsigned short*)(ws + WB_OFF);

  hipMemsetAsync(ws_cnt, 0, B_ * S_ * sizeof(int), stream);
  prep_w_kernel<<<dim3(128), dim3(256), 0, stream>>>(w1, ws_wb);
  scorer_kernel<<<dim3(B_ * S_ / 128), dim3(512), 0, stream>>>(
      x, ws_wb, b1, w2, b2, ws_logits);
  row_kernel<<<dim3(B_), dim3(1024), 0, stream>>>(ws_logits, u, ws_soft, ws_krow, out_ek);
  rank_kernel<<<dim3(16, 4, 8), dim3(256), 0, stream>>>(ws_soft, ws_cnt);
  filter_kernel<<<dim3(B_ * S_), dim3(256), 0, stream>>>(
      x, ws_soft, ws_cnt, ws_krow, out_filt, out_mask);
}

// Round 8
// 311.306 us; speedup vs baseline: 1.2583x; 1.0010x over previous
//
#include <hip/hip_runtime.h>
#include <hip/hip_bf16.h>
#include <math.h>

// Problem constants
#define B_ 8
#define S_ 4096
#define E_ 1024
#define H_ 128
#define MIN_K 32
// d_out layout: filtered [B,S,E] | selection_mask [B,S] | expected_k [B]
#define OUT_MASK_OFF (B_*S_*E_)
#define OUT_EK_OFF   (B_*S_*E_ + B_*S_)

// workspace byte offsets (total 917,536 B)
#define LOGITS_OFF 0
#define SOFT_OFF   131072
#define CNT_OFF    262144
#define KROW_OFF   393216
#define WB_OFF     393248   // 16B aligned; 512 KB tiled split-bf16 weights

typedef __attribute__((ext_vector_type(8))) short   frag8;   // 8 bf16 (4 VGPR)
typedef __attribute__((ext_vector_type(4))) float   fragc;   // 4 f32 acc

static __device__ __forceinline__ unsigned short bf16_rne(float f) {
  unsigned u = __float_as_uint(f);
  unsigned r = u + 0x7FFF + ((u >> 16) & 1);
  return (unsigned short)(r >> 16);
}
static __device__ __forceinline__ float bf16_to_f32(unsigned short h) {
  return __uint_as_float(((unsigned)h) << 16);
}

// ---------------------------------------------------------------------------
// Prep: w1 [E][H] f32 -> wb tiled split-bf16:
//   wb[t][plane][n][k']  t=k-tile (32 tiles of KT=32), plane 0=hi 1=lo,
//   n=0..127, k'=0..31.  Each per-K-step B chunk = 16 KB CONTIGUOUS, so the
//   scorer's staging load is a flat coalesced copy (1 line per 4 lanes).
// ---------------------------------------------------------------------------
__global__ __launch_bounds__(256) void prep_w_kernel(
    const float* __restrict__ w1, unsigned short* __restrict__ wb)
{
  int id = blockIdx.x * 256 + threadIdx.x;       // 0..32767
  int k  = id >> 5;                               // 0..1023
  int n4 = id & 31;                               // 0..31
  float4 w = *(const float4*)(w1 + k * H_ + n4 * 4);
  int t  = k >> 5;          // k-tile
  int kp = k & 31;          // k'
#pragma unroll
  for (int e = 0; e < 4; ++e) {
    float f = (e == 0) ? w.x : (e == 1) ? w.y : (e == 2) ? w.z : w.w;
    unsigned short hi = bf16_rne(f);
    unsigned short lo = bf16_rne(f - bf16_to_f32(hi));
    int n = n4 * 4 + e;
    wb[t * 8192 +        n * 32 + kp] = hi;   // plane 0
    wb[t * 8192 + 4096 + n * 32 + kp] = lo;   // plane 1
  }
}

// ---------------------------------------------------------------------------
// Scorer v7: v6 + RAW barriers (T4, m201/m218 pattern). v6 post-mortem:
// __syncthreads() emits s_waitcnt vmcnt(0) before s_barrier (m97 pathology),
// force-draining the depth-2 prefetch every phase — v1/v5/v6 all converge to
// ~5.3k cy/step because the drain resets the pipeline. Fix: replace the
// K-loop __syncthreads with {lgkmcnt(0); sched_barrier(0); s_barrier;
// sched_barrier(0)}. The compiler's own dependency tracking then emits a
// COUNTED vmcnt(4) before WRITE_STAGE (t+2's 4 loads stay in flight across
// the barrier). lgkmcnt(0) pre-barrier gives cross-wave ds_write visibility;
// buffers alternate read/write exactly as in v6, so barrier ordering logic
// is unchanged. Numerics identical to v5/v6 (same hi/lo bits, MFMA order,
// epilogue tree).
// ---------------------------------------------------------------------------
#define KT 32
#define NTILES (E_ / KT)
#define AS 36   // A LDS stride in floats (144 B: 16B-aligned, 2-way banks = free)
#define XS 40   // B LDS stride in shorts (80 B)

#define ISSUE_LOADS(Sa0, Sa1, Sq0, Sq1, T)                  \
    Sa0 = *(const float4*)(xsrc + (T) * KT);                \
    Sa1 = *(const float4*)(xsrc + (T) * KT + 4);            \
    Sq0 = *(const uint4*)(bsrc + (T) * 8192);               \
    Sq1 = *(const uint4*)(bsrc + (T) * 8192 + 8);

#define WRITE_STAGE(BUF, Sa0, Sa1, Sq0, Sq1) {              \
    *(float4*)&as_f[BUF][aoff]     = Sa0;                   \
    *(float4*)&as_f[BUF][aoff + 4] = Sa1;                   \
    unsigned short* bd_ = bplane ? &bs_lo[BUF][boff]        \
                                 : &bs_hi[BUF][boff];       \
    *(uint4*)(bd_)     = Sq0;                               \
    *(uint4*)(bd_ + 8) = Sq1; }

// raw barrier: LDS-visibility wait only; vmcnt NOT drained (the lever).
#define PHASE_BARRIER()                                     \
    asm volatile("s_waitcnt lgkmcnt(0)" ::: "memory");      \
    __builtin_amdgcn_sched_barrier(0);                      \
    __builtin_amdgcn_s_barrier();                           \
    __builtin_amdgcn_sched_barrier(0);

#define COMPUTE(BUF) {                                                        \
    frag8 ah[2], al[2], bh[4], bl[4];                                         \
    _Pragma("unroll") for (int mt = 0; mt < 2; ++mt) {                        \
      int a_ = (mg * 32 + mt * 16 + l15) * AS + quad * 8;                     \
      float4 f0_ = *(const float4*)&as_f[BUF][a_];                            \
      float4 f1_ = *(const float4*)&as_f[BUF][a_ + 4];                        \
      float ff_[8] = {f0_.x, f0_.y, f0_.z, f0_.w, f1_.x, f1_.y, f1_.z, f1_.w};\
      _Pragma("unroll") for (int e = 0; e < 8; ++e) {                         \
        unsigned short hi_ = bf16_rne(ff_[e]);                                \
        ah[mt][e] = (short)hi_;                                               \
        al[mt][e] = (short)bf16_rne(ff_[e] - bf16_to_f32(hi_)); } }           \
    _Pragma("unroll") for (int nt = 0; nt < 4; ++nt) {                        \
      int a_ = (ng * 64 + nt * 16 + l15) * XS + quad * 8;                     \
      bh[nt] = *(const frag8*)&bs_hi[BUF][a_];                                \
      bl[nt] = *(const frag8*)&bs_lo[BUF][a_]; }                              \
    _Pragma("unroll") for (int mt = 0; mt < 2; ++mt)                          \
      _Pragma("unroll") for (int nt = 0; nt < 4; ++nt) {                      \
        acc[mt][nt] = __builtin_amdgcn_mfma_f32_16x16x32_bf16(ah[mt], bh[nt], acc[mt][nt], 0, 0, 0); \
        acc[mt][nt] = __builtin_amdgcn_mfma_f32_16x16x32_bf16(ah[mt], bl[nt], acc[mt][nt], 0, 0, 0); \
        acc[mt][nt] = __builtin_amdgcn_mfma_f32_16x16x32_bf16(al[mt], bh[nt], acc[mt][nt], 0, 0, 0); } }

__global__ __launch_bounds__(512, 2) void scorer_kernel(
    const float* __restrict__ x,
    const unsigned short* __restrict__ wb,
    const float* __restrict__ b1, const float* __restrict__ w2,
    const float* __restrict__ b2, float* __restrict__ logits)
{
  __shared__ float          as_f[2][128 * AS];
  __shared__ unsigned short bs_hi[2][128 * XS];
  __shared__ unsigned short bs_lo[2][128 * XS];
  __shared__ float part[2][128];

  const int tid  = threadIdx.x;
  const int wv   = tid >> 6;
  const int lane = tid & 63;
  const int l15  = lane & 15;
  const int quad = lane >> 4;
  const int mg   = wv >> 1;          // m-group: rows [mg*32, +32)
  const int ng   = wv & 1;           // n-group: cols [ng*64, +64)
  const int m0   = blockIdx.x * 128;

  // A staging map: thread -> (row r, part p): 8 consecutive floats of row r.
  const int r = tid >> 2, p = tid & 3;
  const float* __restrict__ xsrc = x + (size_t)(m0 + r) * E_ + p * 8;
  // B staging map: flat copy; tid*16 shorts decomposes as plane|n|half.
  const unsigned short* __restrict__ bsrc = wb + tid * 16;
  const int bplane = tid >> 8;              // wave-uniform
  const int boff   = ((tid >> 1) & 127) * XS + (tid & 1) * 16;
  const int aoff   = r * AS + p * 8;        // floats

  fragc acc[2][4];
#pragma unroll
  for (int mt = 0; mt < 2; ++mt)
#pragma unroll
    for (int nt = 0; nt < 4; ++nt)
      acc[mt][nt] = (fragc)(0.f);

  // named stage register sets (rule #20: static, never runtime-indexed)
  float4 a0_S0, a1_S0; uint4 q0_S0, q1_S0;
  float4 a0_S1, a1_S1; uint4 q0_S1, q1_S1;

  // ---- prologue: S0 <- tile0, S1 <- tile1, write S0 -> buf0 ----
  ISSUE_LOADS(a0_S0, a1_S0, q0_S0, q1_S0, 0)
  ISSUE_LOADS(a0_S1, a1_S1, q0_S1, q1_S1, 1)
  WRITE_STAGE(0, a0_S0, a1_S0, q0_S0, q1_S0)
  PHASE_BARRIER()

  // invariant at top of phase computing tile t (buf t&1): regs for t+1 held;
  // issue loads for t+2 now; write t+1 after compute; raw barrier (vmcnt
  // NOT drained -> t+2's loads stay in flight across it).
  for (int tp = 0; tp < 16; ++tp) {
    const bool more = (tp < 15);
    // EVEN phase: tile 2tp from buf0; S1 holds 2tp+1; S0 <- 2tp+2
    if (more) { ISSUE_LOADS(a0_S0, a1_S0, q0_S0, q1_S0, 2 * tp + 2) }
    __builtin_amdgcn_sched_barrier(0);
    COMPUTE(0)
    WRITE_STAGE(1, a0_S1, a1_S1, q0_S1, q1_S1)
    PHASE_BARRIER()
    // ODD phase: tile 2tp+1 from buf1; S0 holds 2tp+2; S1 <- 2tp+3
    if (more) { ISSUE_LOADS(a0_S1, a1_S1, q0_S1, q1_S1, 2 * tp + 3) }
    __builtin_amdgcn_sched_barrier(0);
    COMPUTE(1)
    if (more) { WRITE_STAGE(0, a0_S0, a1_S0, q0_S0, q1_S0) }
    PHASE_BARRIER()
  }

  // Epilogue (v5's exact tree): h = relu(acc + b1[n]); p = sum_nt h*w2[n]
  // (ascending fmaf); 16-lane butterfly (n); cross ng-groups via LDS.
  float b1v[4], w2v[4];
#pragma unroll
  for (int nt = 0; nt < 4; ++nt) {
    int n = ng * 64 + nt * 16 + l15;
    b1v[nt] = b1[n]; w2v[nt] = w2[n];
  }
  float v[2][4];
#pragma unroll
  for (int mt = 0; mt < 2; ++mt)
#pragma unroll
    for (int reg = 0; reg < 4; ++reg) {
      float pacc = 0.f;
#pragma unroll
      for (int nt = 0; nt < 4; ++nt) {
        float h = acc[mt][nt][reg] + b1v[nt];
        h = h > 0.f ? h : 0.f;
        pacc = fmaf(h, w2v[nt], pacc);
      }
      v[mt][reg] = pacc;
    }
#pragma unroll
  for (int mask = 1; mask < 16; mask <<= 1)
#pragma unroll
    for (int mt = 0; mt < 2; ++mt)
#pragma unroll
      for (int reg = 0; reg < 4; ++reg)
        v[mt][reg] += __shfl_xor(v[mt][reg], mask);

  if (l15 == 0) {
#pragma unroll
    for (int mt = 0; mt < 2; ++mt)
#pragma unroll
      for (int reg = 0; reg < 4; ++reg)
        part[ng][mg * 32 + mt * 16 + quad * 4 + reg] = v[mt][reg];
  }
  __syncthreads();
  if (tid < 128)
    logits[m0 + tid] = (part[0][tid] + part[1][tid]) + b2[0];
}

// ---------------------------------------------------------------------------
// Row kernel: expected_k, k, gumbel, softmax. grid=8, block=1024. (unchanged)
// ---------------------------------------------------------------------------
__global__ __launch_bounds__(1024) void row_kernel(
    const float* __restrict__ logits, const float* __restrict__ u,
    float* __restrict__ soft, int* __restrict__ krow, float* __restrict__ ek_out)
{
  const int b = blockIdx.x;
  const int t = threadIdx.x;
  const float* Lrow = logits + b * S_;
  const float* urow = u + b * S_;

  __shared__ double red[1024];
  __shared__ float  redf[1024];

  float z[4];
  double psig = 0.0;
  float zmax = -INFINITY;
#pragma unroll
  for (int i = 0; i < 4; ++i) {
    int j = t + i * 1024;
    float L = Lrow[j];
    float g = -logf(-logf(urow[j]));
    z[i] = L + g;
    psig += (double)(1.f / (1.f + expf(-L)));
    zmax = fmaxf(zmax, z[i]);
  }
  red[t] = psig; redf[t] = zmax;
  __syncthreads();
  for (int s2 = 512; s2 > 0; s2 >>= 1) {
    if (t < s2) { red[t] += red[t + s2]; redf[t] = fmaxf(redf[t], redf[t + s2]); }
    __syncthreads();
  }
  __shared__ float m_sh; __shared__ double ek_sh;
  if (t == 0) { m_sh = redf[0]; ek_sh = red[0]; }
  __syncthreads();
  float m = m_sh;

  float e[4];
  double pexp = 0.0;
#pragma unroll
  for (int i = 0; i < 4; ++i) { e[i] = expf(z[i] - m); pexp += (double)e[i]; }
  red[t] = pexp;
  __syncthreads();
  for (int s2 = 512; s2 > 0; s2 >>= 1) {
    if (t < s2) red[t] += red[t + s2];
    __syncthreads();
  }
  __shared__ float den_sh;
  if (t == 0) den_sh = (float)red[0];
  __syncthreads();
  float den = den_sh;
#pragma unroll
  for (int i = 0; i < 4; ++i) soft[b * S_ + t + i * 1024] = e[i] / den;

  if (t == 0) {
    float ekf = (float)ek_sh;
    int k = (int)ekf;
    if (k < MIN_K) k = MIN_K;
    krow[b] = k;
    ek_out[b] = ekf;
  }
}

// ---------------------------------------------------------------------------
// Rank partial: grid (16 i-chunks, 4 j-chunks, 8 rows). Integer atomicAdd
// (deterministic). j-chunk staged in LDS; all lanes read same addr (broadcast).
// ---------------------------------------------------------------------------
__global__ __launch_bounds__(256) void rank_kernel(
    const float* __restrict__ soft, int* __restrict__ counts)
{
  __shared__ float4 sjs[256];
  const int b  = blockIdx.z;
  const int ic = blockIdx.x;
  const int jc = blockIdx.y;
  const int tid = threadIdx.x;
  const float* row = soft + b * S_;

  sjs[tid] = ((const float4*)row)[jc * 256 + tid];
  const int i = ic * 256 + tid;
  const float si = row[i];
  __syncthreads();

  int cnt = 0;
  const int jbase = jc * 1024;
  for (int j4 = 0; j4 < 256; ++j4) {
    float4 vv = sjs[j4];
    int j = jbase + j4 * 4;
    cnt += (vv.x > si) || (vv.x == si && (j + 0) < i);
    cnt += (vv.y > si) || (vv.y == si && (j + 1) < i);
    cnt += (vv.z > si) || (vv.z == si && (j + 2) < i);
    cnt += (vv.w > si) || (vv.w == si && (j + 3) < i);
  }
  atomicAdd(&counts[b * S_ + i], cnt);
}

// ---------------------------------------------------------------------------
// Filter + mask finalize: one block per token (1024 floats). Uniform scalar
// loads of cnt/k/soft; thread 0 writes selection_mask.
// ---------------------------------------------------------------------------
__global__ __launch_bounds__(256) void filter_kernel(
    const float* __restrict__ x, const float* __restrict__ soft,
    const int* __restrict__ counts, const int* __restrict__ krow,
    float* __restrict__ out, float* __restrict__ mask_out)
{
  const int token = blockIdx.x;           // 0..32767
  const int b = token >> 12;              // S_=4096
  const float s = soft[token];
  const float h = (counts[token] < krow[b]) ? 1.f : 0.f;
  const float sel = (h - s) + s;

  size_t base = (size_t)token * (E_ / 4) + threadIdx.x;
  float4 v = ((const float4*)x)[base];
  v.x *= sel; v.y *= sel; v.z *= sel; v.w *= sel;
  ((float4*)out)[base] = v;
  if (threadIdx.x == 0) mask_out[token] = sel;
}

// ---------------------------------------------------------------------------
extern "C" void kernel_launch(void* const* d_in, const int* in_sizes, int n_in,
                              void* d_out, int out_size, void* d_ws, size_t ws_size,
                              hipStream_t stream) {
  const float* x  = (const float*)d_in[0];
  const float* w1 = (const float*)d_in[1];
  const float* b1 = (const float*)d_in[2];
  const float* w2 = (const float*)d_in[3];
  const float* b2 = (const float*)d_in[4];
  const float* u  = (const float*)d_in[5];

  float* out = (float*)d_out;
  float* out_filt = out;
  float* out_mask = out + OUT_MASK_OFF;
  float* out_ek   = out + OUT_EK_OFF;

  char* ws = (char*)d_ws;
  float*          ws_logits = (float*)(ws + LOGITS_OFF);
  float*          ws_soft   = (float*)(ws + SOFT_OFF);
  int*            ws_cnt    = (int*)(ws + CNT_OFF);
  int*            ws_krow   = (int*)(ws + KROW_OFF);
  unsigned short* ws_wb     = (unsigned short*)(ws + WB_OFF);

  hipMemsetAsync(ws_cnt, 0, B_ * S_ * sizeof(int), stream);
  prep_w_kernel<<<dim3(128), dim3(256), 0, stream>>>(w1, ws_wb);
  scorer_kernel<<<dim3(B_ * S_ / 128), dim3(512), 0, stream>>>(
      x, ws_wb, b1, w2, b2, ws_logits);
  row_kernel<<<dim3(B_), dim3(1024), 0, stream>>>(ws_logits, u, ws_soft, ws_krow, out_ek);
  rank_kernel<<<dim3(16, 4, 8), dim3(256), 0, stream>>>(ws_soft, ws_cnt);
  filter_kernel<<<dim3(B_ * S_), dim3(256), 0, stream>>>(
      x, ws_soft, ws_cnt, ws_krow, out_filt, out_mask);
}

// Round 9
// 307.924 us; speedup vs baseline: 1.2721x; 1.0110x over previous
//
#include <hip/hip_runtime.h>
#include <hip/hip_bf16.h>
#include <math.h>

// Problem constants
#define B_ 8
#define S_ 4096
#define E_ 1024
#define H_ 128
#define MIN_K 32
// d_out layout: filtered [B,S,E] | selection_mask [B,S] | expected_k [B]
#define OUT_MASK_OFF (B_*S_*E_)
#define OUT_EK_OFF   (B_*S_*E_ + B_*S_)

// workspace byte offsets (total 917,536 B)
#define LOGITS_OFF 0
#define SOFT_OFF   131072
#define CNT_OFF    262144
#define KROW_OFF   393216
#define WB_OFF     393248   // 16B aligned; 512 KB tiled split-bf16 weights

typedef __attribute__((ext_vector_type(8))) short   frag8;   // 8 bf16 (4 VGPR)
typedef __attribute__((ext_vector_type(4))) float   fragc;   // 4 f32 acc

static __device__ __forceinline__ unsigned short bf16_rne(float f) {
  unsigned u = __float_as_uint(f);
  unsigned r = u + 0x7FFF + ((u >> 16) & 1);
  return (unsigned short)(r >> 16);
}
static __device__ __forceinline__ float bf16_to_f32(unsigned short h) {
  return __uint_as_float(((unsigned)h) << 16);
}

// ---------------------------------------------------------------------------
// Prep: w1 [E][H] f32 -> wb tiled split-bf16:
//   wb[t][plane][n][k']  t=k-tile (32 tiles of KT=32), plane 0=hi 1=lo,
//   n=0..127, k'=0..31.  Each per-K-step B chunk = 16 KB CONTIGUOUS, so the
//   scorer's staging load is a flat coalesced copy (1 line per 4 lanes).
// ---------------------------------------------------------------------------
__global__ __launch_bounds__(256) void prep_w_kernel(
    const float* __restrict__ w1, unsigned short* __restrict__ wb)
{
  int id = blockIdx.x * 256 + threadIdx.x;       // 0..32767
  int k  = id >> 5;                               // 0..1023
  int n4 = id & 31;                               // 0..31
  float4 w = *(const float4*)(w1 + k * H_ + n4 * 4);
  int t  = k >> 5;          // k-tile
  int kp = k & 31;          // k'
#pragma unroll
  for (int e = 0; e < 4; ++e) {
    float f = (e == 0) ? w.x : (e == 1) ? w.y : (e == 2) ? w.z : w.w;
    unsigned short hi = bf16_rne(f);
    unsigned short lo = bf16_rne(f - bf16_to_f32(hi));
    int n = n4 * 4 + e;
    wb[t * 8192 +        n * 32 + kp] = hi;   // plane 0
    wb[t * 8192 + 4096 + n * 32 + kp] = lo;   // plane 1
  }
}

// ---------------------------------------------------------------------------
// Scorer v8: v7's fetch-once pipeline at 2 BLOCKS/CU. v7 post-mortem: with
// 1 block/CU, every barrier is a full-CU stall (5.3k cy/phase vs ~1.6k
// LDS+MFMA floor) — raw barriers/counted vmcnt didn't help because no other
// BLOCK exists to fill the hole. m97/m114 evidence: the naive 2-barrier loop
// at 3 blocks/CU reaches 37% MfmaUtil purely via implicit cross-block wave
// overlap. Fix: M=64, 256 thr (4 waves: 2mg x 2ng), grid 512 = 2 blocks/CU
// (LDS 60 KB/block -> exactly 2 fit). Per-wave code IDENTICAL to v7
// (32m x 64n, 24 MFMA/step, same epilogue) -> logits bitwise identical.
// Blocks drift half a phase apart; each fills the other's barrier stalls.
// ---------------------------------------------------------------------------
#define KT 32
#define NTILES (E_ / KT)
#define AS 36   // A LDS stride in floats (144 B: 16B-aligned, 2-way banks = free)
#define XS 40   // B LDS stride in shorts (80 B)

// per-thread stage: A = 2 float4 (32B of one x-row), B = 4 uint4 (4 flat
// 16B chunks of the wb tile: i -> plane i>>1, n = (tid>>2)+((i&1)<<6), cw).
#define ISSUE_LOADS(Sa0, Sa1, Sq0, Sq1, Sq2, Sq3, T)        \
    Sa0 = *(const float4*)(xsrc + (T) * KT);                \
    Sa1 = *(const float4*)(xsrc + (T) * KT + 4);            \
    Sq0 = *(const uint4*)(bsrc + (T) * 8192);               \
    Sq1 = *(const uint4*)(bsrc + (T) * 8192 + 2048);        \
    Sq2 = *(const uint4*)(bsrc + (T) * 8192 + 4096);        \
    Sq3 = *(const uint4*)(bsrc + (T) * 8192 + 6144);

#define WRITE_STAGE(BUF, Sa0, Sa1, Sq0, Sq1, Sq2, Sq3) {    \
    *(float4*)&as_f[BUF][aoff]     = Sa0;                   \
    *(float4*)&as_f[BUF][aoff + 4] = Sa1;                   \
    *(uint4*)&bs_hi[BUF][boffA] = Sq0;                      \
    *(uint4*)&bs_hi[BUF][boffB] = Sq1;                      \
    *(uint4*)&bs_lo[BUF][boffA] = Sq2;                      \
    *(uint4*)&bs_lo[BUF][boffB] = Sq3; }

// raw barrier: LDS-visibility wait only; vmcnt NOT drained.
#define PHASE_BARRIER()                                     \
    asm volatile("s_waitcnt lgkmcnt(0)" ::: "memory");      \
    __builtin_amdgcn_sched_barrier(0);                      \
    __builtin_amdgcn_s_barrier();                           \
    __builtin_amdgcn_sched_barrier(0);

#define COMPUTE(BUF) {                                                        \
    frag8 ah[2], al[2], bh[4], bl[4];                                         \
    _Pragma("unroll") for (int mt = 0; mt < 2; ++mt) {                        \
      int a_ = (mg * 32 + mt * 16 + l15) * AS + quad * 8;                     \
      float4 f0_ = *(const float4*)&as_f[BUF][a_];                            \
      float4 f1_ = *(const float4*)&as_f[BUF][a_ + 4];                        \
      float ff_[8] = {f0_.x, f0_.y, f0_.z, f0_.w, f1_.x, f1_.y, f1_.z, f1_.w};\
      _Pragma("unroll") for (int e = 0; e < 8; ++e) {                         \
        unsigned short hi_ = bf16_rne(ff_[e]);                                \
        ah[mt][e] = (short)hi_;                                               \
        al[mt][e] = (short)bf16_rne(ff_[e] - bf16_to_f32(hi_)); } }           \
    _Pragma("unroll") for (int nt = 0; nt < 4; ++nt) {                        \
      int a_ = (ng * 64 + nt * 16 + l15) * XS + quad * 8;                     \
      bh[nt] = *(const frag8*)&bs_hi[BUF][a_];                                \
      bl[nt] = *(const frag8*)&bs_lo[BUF][a_]; }                              \
    _Pragma("unroll") for (int mt = 0; mt < 2; ++mt)                          \
      _Pragma("unroll") for (int nt = 0; nt < 4; ++nt) {                      \
        acc[mt][nt] = __builtin_amdgcn_mfma_f32_16x16x32_bf16(ah[mt], bh[nt], acc[mt][nt], 0, 0, 0); \
        acc[mt][nt] = __builtin_amdgcn_mfma_f32_16x16x32_bf16(ah[mt], bl[nt], acc[mt][nt], 0, 0, 0); \
        acc[mt][nt] = __builtin_amdgcn_mfma_f32_16x16x32_bf16(al[mt], bh[nt], acc[mt][nt], 0, 0, 0); } }

__global__ __launch_bounds__(256, 2) void scorer_kernel(
    const float* __restrict__ x,
    const unsigned short* __restrict__ wb,
    const float* __restrict__ b1, const float* __restrict__ w2,
    const float* __restrict__ b2, float* __restrict__ logits)
{
  __shared__ float          as_f[2][64 * AS];
  __shared__ unsigned short bs_hi[2][128 * XS];
  __shared__ unsigned short bs_lo[2][128 * XS];
  __shared__ float part[2][64];

  const int tid  = threadIdx.x;
  const int wv   = tid >> 6;
  const int lane = tid & 63;
  const int l15  = lane & 15;
  const int quad = lane >> 4;
  const int mg   = wv >> 1;          // m-group: rows [mg*32, +32)
  const int ng   = wv & 1;           // n-group: cols [ng*64, +64)
  const int m0   = blockIdx.x * 64;

  // A staging map: thread -> (row r, part p): 8 consecutive floats of row r.
  const int r = tid >> 2, p = tid & 3;
  const float* __restrict__ xsrc = x + (size_t)(m0 + r) * E_ + p * 8;
  // B staging map: 4 flat 16B chunks/thread. Chunk i: global short offset
  // (tid + i*256)*8; plane = i>>1; n = (tid>>2) + ((i&1)<<6); cw = tid&3.
  const unsigned short* __restrict__ bsrc = wb + tid * 8;
  const int bn0   = tid >> 2, bcw = tid & 3;
  const int boffA = bn0 * XS + bcw * 8;          // n in [0,64)
  const int boffB = (bn0 + 64) * XS + bcw * 8;   // n in [64,128)
  const int aoff  = r * AS + p * 8;              // floats

  fragc acc[2][4];
#pragma unroll
  for (int mt = 0; mt < 2; ++mt)
#pragma unroll
    for (int nt = 0; nt < 4; ++nt)
      acc[mt][nt] = (fragc)(0.f);

  // named stage register sets (rule #20: static, never runtime-indexed)
  float4 a0_S0, a1_S0; uint4 q0_S0, q1_S0, q2_S0, q3_S0;
  float4 a0_S1, a1_S1; uint4 q0_S1, q1_S1, q2_S1, q3_S1;

  // ---- prologue: S0 <- tile0, S1 <- tile1, write S0 -> buf0 ----
  ISSUE_LOADS(a0_S0, a1_S0, q0_S0, q1_S0, q2_S0, q3_S0, 0)
  ISSUE_LOADS(a0_S1, a1_S1, q0_S1, q1_S1, q2_S1, q3_S1, 1)
  WRITE_STAGE(0, a0_S0, a1_S0, q0_S0, q1_S0, q2_S0, q3_S0)
  PHASE_BARRIER()

  // invariant at top of phase computing tile t (buf t&1): regs for t+1 held;
  // issue loads for t+2 now; write t+1 after compute; raw barrier (vmcnt
  // NOT drained -> t+2's loads stay in flight across it).
  for (int tp = 0; tp < 16; ++tp) {
    const bool more = (tp < 15);
    // EVEN phase: tile 2tp from buf0; S1 holds 2tp+1; S0 <- 2tp+2
    if (more) { ISSUE_LOADS(a0_S0, a1_S0, q0_S0, q1_S0, q2_S0, q3_S0, 2 * tp + 2) }
    __builtin_amdgcn_sched_barrier(0);
    COMPUTE(0)
    WRITE_STAGE(1, a0_S1, a1_S1, q0_S1, q1_S1, q2_S1, q3_S1)
    PHASE_BARRIER()
    // ODD phase: tile 2tp+1 from buf1; S0 holds 2tp+2; S1 <- 2tp+3
    if (more) { ISSUE_LOADS(a0_S1, a1_S1, q0_S1, q1_S1, q2_S1, q3_S1, 2 * tp + 3) }
    __builtin_amdgcn_sched_barrier(0);
    COMPUTE(1)
    if (more) { WRITE_STAGE(0, a0_S0, a1_S0, q0_S0, q1_S0, q2_S0, q3_S0) }
    PHASE_BARRIER()
  }

  // Epilogue (v5/v7's exact tree): h = relu(acc + b1[n]); p = sum_nt h*w2[n]
  // (ascending fmaf); 16-lane butterfly (n); cross ng-groups via LDS.
  float b1v[4], w2v[4];
#pragma unroll
  for (int nt = 0; nt < 4; ++nt) {
    int n = ng * 64 + nt * 16 + l15;
    b1v[nt] = b1[n]; w2v[nt] = w2[n];
  }
  float v[2][4];
#pragma unroll
  for (int mt = 0; mt < 2; ++mt)
#pragma unroll
    for (int reg = 0; reg < 4; ++reg) {
      float pacc = 0.f;
#pragma unroll
      for (int nt = 0; nt < 4; ++nt) {
        float h = acc[mt][nt][reg] + b1v[nt];
        h = h > 0.f ? h : 0.f;
        pacc = fmaf(h, w2v[nt], pacc);
      }
      v[mt][reg] = pacc;
    }
#pragma unroll
  for (int mask = 1; mask < 16; mask <<= 1)
#pragma unroll
    for (int mt = 0; mt < 2; ++mt)
#pragma unroll
      for (int reg = 0; reg < 4; ++reg)
        v[mt][reg] += __shfl_xor(v[mt][reg], mask);

  if (l15 == 0) {
#pragma unroll
    for (int mt = 0; mt < 2; ++mt)
#pragma unroll
      for (int reg = 0; reg < 4; ++reg)
        part[ng][mg * 32 + mt * 16 + quad * 4 + reg] = v[mt][reg];
  }
  __syncthreads();
  if (tid < 64)
    logits[m0 + tid] = (part[0][tid] + part[1][tid]) + b2[0];
}

// ---------------------------------------------------------------------------
// Row kernel: expected_k, k, gumbel, softmax. grid=8, block=1024. (unchanged)
// ---------------------------------------------------------------------------
__global__ __launch_bounds__(1024) void row_kernel(
    const float* __restrict__ logits, const float* __restrict__ u,
    float* __restrict__ soft, int* __restrict__ krow, float* __restrict__ ek_out)
{
  const int b = blockIdx.x;
  const int t = threadIdx.x;
  const float* Lrow = logits + b * S_;
  const float* urow = u + b * S_;

  __shared__ double red[1024];
  __shared__ float  redf[1024];

  float z[4];
  double psig = 0.0;
  float zmax = -INFINITY;
#pragma unroll
  for (int i = 0; i < 4; ++i) {
    int j = t + i * 1024;
    float L = Lrow[j];
    float g = -logf(-logf(urow[j]));
    z[i] = L + g;
    psig += (double)(1.f / (1.f + expf(-L)));
    zmax = fmaxf(zmax, z[i]);
  }
  red[t] = psig; redf[t] = zmax;
  __syncthreads();
  for (int s2 = 512; s2 > 0; s2 >>= 1) {
    if (t < s2) { red[t] += red[t + s2]; redf[t] = fmaxf(redf[t], redf[t + s2]); }
    __syncthreads();
  }
  __shared__ float m_sh; __shared__ double ek_sh;
  if (t == 0) { m_sh = redf[0]; ek_sh = red[0]; }
  __syncthreads();
  float m = m_sh;

  float e[4];
  double pexp = 0.0;
#pragma unroll
  for (int i = 0; i < 4; ++i) { e[i] = expf(z[i] - m); pexp += (double)e[i]; }
  red[t] = pexp;
  __syncthreads();
  for (int s2 = 512; s2 > 0; s2 >>= 1) {
    if (t < s2) red[t] += red[t + s2];
    __syncthreads();
  }
  __shared__ float den_sh;
  if (t == 0) den_sh = (float)red[0];
  __syncthreads();
  float den = den_sh;
#pragma unroll
  for (int i = 0; i < 4; ++i) soft[b * S_ + t + i * 1024] = e[i] / den;

  if (t == 0) {
    float ekf = (float)ek_sh;
    int k = (int)ekf;
    if (k < MIN_K) k = MIN_K;
    krow[b] = k;
    ek_out[b] = ekf;
  }
}

// ---------------------------------------------------------------------------
// Rank partial: grid (16 i-chunks, 4 j-chunks, 8 rows). Integer atomicAdd
// (deterministic). j-chunk staged in LDS; all lanes read same addr (broadcast).
// ---------------------------------------------------------------------------
__global__ __launch_bounds__(256) void rank_kernel(
    const float* __restrict__ soft, int* __restrict__ counts)
{
  __shared__ float4 sjs[256];
  const int b  = blockIdx.z;
  const int ic = blockIdx.x;
  const int jc = blockIdx.y;
  const int tid = threadIdx.x;
  const float* row = soft + b * S_;

  sjs[tid] = ((const float4*)row)[jc * 256 + tid];
  const int i = ic * 256 + tid;
  const float si = row[i];
  __syncthreads();

  int cnt = 0;
  const int jbase = jc * 1024;
  for (int j4 = 0; j4 < 256; ++j4) {
    float4 vv = sjs[j4];
    int j = jbase + j4 * 4;
    cnt += (vv.x > si) || (vv.x == si && (j + 0) < i);
    cnt += (vv.y > si) || (vv.y == si && (j + 1) < i);
    cnt += (vv.z > si) || (vv.z == si && (j + 2) < i);
    cnt += (vv.w > si) || (vv.w == si && (j + 3) < i);
  }
  atomicAdd(&counts[b * S_ + i], cnt);
}

// ---------------------------------------------------------------------------
// Filter + mask finalize: one block per token (1024 floats). Uniform scalar
// loads of cnt/k/soft; thread 0 writes selection_mask.
// ---------------------------------------------------------------------------
__global__ __launch_bounds__(256) void filter_kernel(
    const float* __restrict__ x, const float* __restrict__ soft,
    const int* __restrict__ counts, const int* __restrict__ krow,
    float* __restrict__ out, float* __restrict__ mask_out)
{
  const int token = blockIdx.x;           // 0..32767
  const int b = token >> 12;              // S_=4096
  const float s = soft[token];
  const float h = (counts[token] < krow[b]) ? 1.f : 0.f;
  const float sel = (h - s) + s;

  size_t base = (size_t)token * (E_ / 4) + threadIdx.x;
  float4 v = ((const float4*)x)[base];
  v.x *= sel; v.y *= sel; v.z *= sel; v.w *= sel;
  ((float4*)out)[base] = v;
  if (threadIdx.x == 0) mask_out[token] = sel;
}

// ---------------------------------------------------------------------------
extern "C" void kernel_launch(void* const* d_in, const int* in_sizes, int n_in,
                              void* d_out, int out_size, void* d_ws, size_t ws_size,
                              hipStream_t stream) {
  const float* x  = (const float*)d_in[0];
  const float* w1 = (const float*)d_in[1];
  const float* b1 = (const float*)d_in[2];
  const float* w2 = (const float*)d_in[3];
  const float* b2 = (const float*)d_in[4];
  const float* u  = (const float*)d_in[5];

  float* out = (float*)d_out;
  float* out_filt = out;
  float* out_mask = out + OUT_MASK_OFF;
  float* out_ek   = out + OUT_EK_OFF;

  char* ws = (char*)d_ws;
  float*          ws_logits = (float*)(ws + LOGITS_OFF);
  float*          ws_soft   = (float*)(ws + SOFT_OFF);
  int*            ws_cnt    = (int*)(ws + CNT_OFF);
  int*            ws_krow   = (int*)(ws + KROW_OFF);
  unsigned short* ws_wb     = (unsigned short*)(ws + WB_OFF);

  hipMemsetAsync(ws_cnt, 0, B_ * S_ * sizeof(int), stream);
  prep_w_kernel<<<dim3(128), dim3(256), 0, stream>>>(w1, ws_wb);
  scorer_kernel<<<dim3(B_ * S_ / 64), dim3(256), 0, stream>>>(
      x, ws_wb, b1, w2, b2, ws_logits);
  row_kernel<<<dim3(B_), dim3(1024), 0, stream>>>(ws_logits, u, ws_soft, ws_krow, out_ek);
  rank_kernel<<<dim3(16, 4, 8), dim3(256), 0, stream>>>(ws_soft, ws_cnt);
  filter_kernel<<<dim3(B_ * S_), dim3(256), 0, stream>>>(
      x, ws_soft, ws_cnt, ws_krow, out_filt, out_mask);
}